// Round 1
// baseline (14520.595 us; speedup 1.0000x reference)
//
#include <hip/hip_runtime.h>
#include <cstddef>

#define BATCH 64
#define SEQL  197
#define EMB   768
#define NH    12
#define HDIM  64
#define NBLK  6
#define MLPD  3072
#define TOKS  12608   // BATCH*SEQL
#define PTOK  12544   // BATCH*196
#define ATT_SCALE 0.28867513459481287f  // 1/sqrt(H=12)

__device__ inline float bf2f(unsigned short u) {
  union { unsigned int i; float f; } c; c.i = ((unsigned int)u) << 16; return c.f;
}
__device__ inline unsigned short f2bf(float f) {
  union { float f; unsigned int i; } c; c.f = f;
  unsigned int r = c.i + 0x7FFFu + ((c.i >> 16) & 1u);
  return (unsigned short)(r >> 16);
}

// ---------------- patchify: images (B,3,224,224) -> patches (12544, 768) ----------------
__global__ __launch_bounds__(256) void patchify_kernel(const float* __restrict__ img,
                                                       float* __restrict__ out) {
  int i4 = blockIdx.x * 256 + threadIdx.x;    // 0 .. 2,408,447  (12544*768/4)
  int f4 = i4 % 192;
  int r  = i4 / 192;
  int b  = r / 196, t = r - b * 196;
  int f  = f4 * 4;
  int c  = f >> 8;
  int rem = f & 255;
  int iy = rem >> 4, ix = rem & 15;
  int py = t / 14, px = t - py * 14;
  const float* src = img + ((((size_t)b * 3 + c) * 224 + py * 16 + iy) * 224 + px * 16 + ix);
  *(float4*)(out + (size_t)r * 768 + f) = *(const float4*)src;
}

// ---------------- cls token + pos row 0 ----------------
__global__ __launch_bounds__(256) void clspos_kernel(const float* __restrict__ cls,
                                                     const float* __restrict__ pos,
                                                     float* __restrict__ X) {
  int idx = blockIdx.x * 256 + threadIdx.x;   // < 64*768
  int b = idx / 768, e = idx - b * 768;
  X[(size_t)b * SEQL * 768 + e] = cls[e] + pos[e];
}

// ---------------- generic 128x128x8 fp32 GEMM, templated epilogue ----------------
// MODE 0: patch embed -> X rows remapped b*197+1+t, += bmap + pos[1+t]
// MODE 1: C = gelu(A@B + bias)          (mid, N=3072)
// MODE 2: C += A@B + bias               (residual into X, N=768)
template<int MODE>
__global__ __launch_bounds__(256) void gemm128(const float* __restrict__ A,
                                               const float* __restrict__ B,
                                               float* __restrict__ C,
                                               const float* __restrict__ bias,
                                               const float* __restrict__ pos,
                                               int M, int N, int K) {
  __shared__ float As[8][128];
  __shared__ float Bs[8][128];
  const int tid = threadIdx.x;
  const int m0 = blockIdx.y * 128;
  const int n0 = blockIdx.x * 128;
  const int la_m = tid >> 1;
  const int la_k = (tid & 1) * 4;
  const int lb_k = tid >> 5;
  const int lb_n = (tid & 31) * 4;
  const int tr = (tid >> 4) * 8;
  const int tc = (tid & 15) * 8;
  float acc[8][8];
#pragma unroll
  for (int i = 0; i < 8; ++i)
#pragma unroll
    for (int j = 0; j < 8; ++j) acc[i][j] = 0.f;

  for (int k0 = 0; k0 < K; k0 += 8) {
    float4 av = make_float4(0.f, 0.f, 0.f, 0.f);
    int am = m0 + la_m;
    if (am < M) av = *(const float4*)(A + (size_t)am * K + (k0 + la_k));
    As[la_k + 0][la_m] = av.x;
    As[la_k + 1][la_m] = av.y;
    As[la_k + 2][la_m] = av.z;
    As[la_k + 3][la_m] = av.w;
    *(float4*)&Bs[lb_k][lb_n] = *(const float4*)(B + (size_t)(k0 + lb_k) * N + (n0 + lb_n));
    __syncthreads();
#pragma unroll
    for (int k = 0; k < 8; ++k) {
      float a[8], bb[8];
      *(float4*)&a[0]  = *(float4*)&As[k][tr];
      *(float4*)&a[4]  = *(float4*)&As[k][tr + 4];
      *(float4*)&bb[0] = *(float4*)&Bs[k][tc];
      *(float4*)&bb[4] = *(float4*)&Bs[k][tc + 4];
#pragma unroll
      for (int i = 0; i < 8; ++i)
#pragma unroll
        for (int j = 0; j < 8; ++j) acc[i][j] += a[i] * bb[j];
    }
    __syncthreads();
  }

#pragma unroll
  for (int i = 0; i < 8; ++i) {
    int r = m0 + tr + i;
    if (r >= M) continue;
    if (MODE == 0) {
      int b = r / 196, t = r - b * 196;
      size_t xrow = (size_t)b * SEQL + 1 + t;
      float* dst = C + xrow * 768 + n0 + tc;
      const float* pp = pos + (size_t)(1 + t) * 768 + n0 + tc;
      const float* bi = bias + n0 + tc;
      float4 o0, o1;
      o0.x = acc[i][0] + bi[0] + pp[0]; o0.y = acc[i][1] + bi[1] + pp[1];
      o0.z = acc[i][2] + bi[2] + pp[2]; o0.w = acc[i][3] + bi[3] + pp[3];
      o1.x = acc[i][4] + bi[4] + pp[4]; o1.y = acc[i][5] + bi[5] + pp[5];
      o1.z = acc[i][6] + bi[6] + pp[6]; o1.w = acc[i][7] + bi[7] + pp[7];
      *(float4*)&dst[0] = o0; *(float4*)&dst[4] = o1;
    } else if (MODE == 1) {
      float* dst = C + (size_t)r * MLPD + n0 + tc;
      const float* bi = bias + n0 + tc;
      float4 o0, o1;
      float v[8];
#pragma unroll
      for (int j = 0; j < 8; ++j) {
        float x = acc[i][j] + bi[j];
        v[j] = 0.5f * x * (1.f + erff(x * 0.70710678118654752f));
      }
      o0.x = v[0]; o0.y = v[1]; o0.z = v[2]; o0.w = v[3];
      o1.x = v[4]; o1.y = v[5]; o1.z = v[6]; o1.w = v[7];
      *(float4*)&dst[0] = o0; *(float4*)&dst[4] = o1;
    } else {
      float* dst = C + (size_t)r * 768 + n0 + tc;
      const float* bi = bias + n0 + tc;
      float4 c0 = *(float4*)&dst[0];
      float4 c1 = *(float4*)&dst[4];
      c0.x += acc[i][0] + bi[0]; c0.y += acc[i][1] + bi[1];
      c0.z += acc[i][2] + bi[2]; c0.w += acc[i][3] + bi[3];
      c1.x += acc[i][4] + bi[4]; c1.y += acc[i][5] + bi[5];
      c1.z += acc[i][6] + bi[6]; c1.w += acc[i][7] + bi[7];
      *(float4*)&dst[0] = c0; *(float4*)&dst[4] = c1;
    }
  }
}

// ---------------- LayerNorm: one wave per token ----------------
__global__ __launch_bounds__(256) void ln_kernel(const float* __restrict__ Xi,
                                                 float* __restrict__ Ho,
                                                 const float* __restrict__ g,
                                                 const float* __restrict__ bb) {
  int tok = blockIdx.x * 4 + (threadIdx.x >> 6);
  int lane = threadIdx.x & 63;
  const float* x = Xi + (size_t)tok * 768;
  float4 v0 = *(const float4*)(x + lane * 4);
  float4 v1 = *(const float4*)(x + 256 + lane * 4);
  float4 v2 = *(const float4*)(x + 512 + lane * 4);
  float s = v0.x + v0.y + v0.z + v0.w + v1.x + v1.y + v1.z + v1.w + v2.x + v2.y + v2.z + v2.w;
  float q = v0.x*v0.x + v0.y*v0.y + v0.z*v0.z + v0.w*v0.w
          + v1.x*v1.x + v1.y*v1.y + v1.z*v1.z + v1.w*v1.w
          + v2.x*v2.x + v2.y*v2.y + v2.z*v2.z + v2.w*v2.w;
#pragma unroll
  for (int o = 32; o > 0; o >>= 1) { s += __shfl_xor(s, o); q += __shfl_xor(q, o); }
  float mean = s * (1.f / 768.f);
  float var  = q * (1.f / 768.f) - mean * mean;
  float rs = rsqrtf(var + 1e-5f);
  float* outp = Ho + (size_t)tok * 768;
  float4 g0 = *(const float4*)(g + lane * 4);
  float4 g1 = *(const float4*)(g + 256 + lane * 4);
  float4 g2 = *(const float4*)(g + 512 + lane * 4);
  float4 b0 = *(const float4*)(bb + lane * 4);
  float4 b1 = *(const float4*)(bb + 256 + lane * 4);
  float4 b2 = *(const float4*)(bb + 512 + lane * 4);
  float4 o0, o1, o2;
  o0.x = (v0.x - mean) * rs * g0.x + b0.x; o0.y = (v0.y - mean) * rs * g0.y + b0.y;
  o0.z = (v0.z - mean) * rs * g0.z + b0.z; o0.w = (v0.w - mean) * rs * g0.w + b0.w;
  o1.x = (v1.x - mean) * rs * g1.x + b1.x; o1.y = (v1.y - mean) * rs * g1.y + b1.y;
  o1.z = (v1.z - mean) * rs * g1.z + b1.z; o1.w = (v1.w - mean) * rs * g1.w + b1.w;
  o2.x = (v2.x - mean) * rs * g2.x + b2.x; o2.y = (v2.y - mean) * rs * g2.y + b2.y;
  o2.z = (v2.z - mean) * rs * g2.z + b2.z; o2.w = (v2.w - mean) * rs * g2.w + b2.w;
  *(float4*)(outp + lane * 4) = o0;
  *(float4*)(outp + 256 + lane * 4) = o1;
  *(float4*)(outp + 512 + lane * 4) = o2;
}

// ---------------- per-head QKV: block = (32 tokens, head h) ----------------
__global__ __launch_bounds__(256) void qkv_kernel(const float* __restrict__ Hb,
    const float* __restrict__ Wq, const float* __restrict__ bq,
    const float* __restrict__ Wk, const float* __restrict__ bk,
    const float* __restrict__ Wv, const float* __restrict__ bv,
    float* __restrict__ Qo, float* __restrict__ Ko, float* __restrict__ Vo) {
  __shared__ float xs[32][68];          // padded: conflict-free b128 reads
  __shared__ float ws[3][64][64];
  const int h = blockIdx.y;
  const int tk0 = blockIdx.x * 32;
  const int tid = threadIdx.x;
  {
    int tok = tid >> 3;
    int p = (tid & 7) * 8;
    const float* src = Hb + (size_t)(tk0 + tok) * 768 + h * 64 + p;
    *(float4*)&xs[tok][p]     = *(const float4*)src;
    *(float4*)&xs[tok][p + 4] = *(const float4*)(src + 4);
  }
  {
    const float* w0 = Wq + (size_t)h * 4096;
    const float* w1 = Wk + (size_t)h * 4096;
    const float* w2 = Wv + (size_t)h * 4096;
    int base = tid * 16;
    float* wf = &ws[0][0][0];
#pragma unroll
    for (int j = 0; j < 16; j += 4) {
      *(float4*)(wf + base + j)            = *(const float4*)(w0 + base + j);
      *(float4*)(wf + 4096 + base + j)     = *(const float4*)(w1 + base + j);
      *(float4*)(wf + 8192 + base + j)     = *(const float4*)(w2 + base + j);
    }
  }
  __syncthreads();
  const int e4 = (tid & 15) * 4;
  const int t2 = (tid >> 4) * 2;
  float acc[3][2][4];
#pragma unroll
  for (int m = 0; m < 3; ++m)
#pragma unroll
    for (int ti = 0; ti < 2; ++ti)
#pragma unroll
      for (int j = 0; j < 4; ++j) acc[m][ti][j] = 0.f;

#pragma unroll 4
  for (int d4 = 0; d4 < 16; ++d4) {
    float x0[4], x1[4];
    *(float4*)x0 = *(float4*)&xs[t2][d4 * 4];
    *(float4*)x1 = *(float4*)&xs[t2 + 1][d4 * 4];
#pragma unroll
    for (int m = 0; m < 3; ++m)
#pragma unroll
      for (int dj = 0; dj < 4; ++dj) {
        float4 w = *(float4*)&ws[m][d4 * 4 + dj][e4];
        acc[m][0][0] += x0[dj] * w.x; acc[m][0][1] += x0[dj] * w.y;
        acc[m][0][2] += x0[dj] * w.z; acc[m][0][3] += x0[dj] * w.w;
        acc[m][1][0] += x1[dj] * w.x; acc[m][1][1] += x1[dj] * w.y;
        acc[m][1][2] += x1[dj] * w.z; acc[m][1][3] += x1[dj] * w.w;
      }
  }
#pragma unroll
  for (int m = 0; m < 3; ++m) {
    const float* bptr = (m == 0 ? bq : (m == 1 ? bk : bv)) + h * 64 + e4;
    float* optr = (m == 0 ? Qo : (m == 1 ? Ko : Vo));
#pragma unroll
    for (int ti = 0; ti < 2; ++ti) {
      int tk = tk0 + t2 + ti;
      int b = tk / 197, s = tk - b * 197;
      size_t base_o = (((size_t)b * NH + h) * SEQL + s) * 64 + e4;
      float4 o;
      o.x = acc[m][ti][0] + bptr[0];
      o.y = acc[m][ti][1] + bptr[1];
      o.z = acc[m][ti][2] + bptr[2];
      o.w = acc[m][ti][3] + bptr[3];
      *(float4*)&optr[base_o] = o;
    }
  }
}

// ---------------- attention: one WG per (b,h); K/V staged bf16 in LDS ----------------
__global__ __launch_bounds__(256) void attn_kernel(const float* __restrict__ Q,
                                                   const float* __restrict__ Kg,
                                                   const float* __restrict__ Vg,
                                                   float* __restrict__ X) {
  __shared__ unsigned short Ks[197][68];   // rows 136B: b64 reads 2-way (free)
  __shared__ unsigned short Vt[64][198];   // rows 396B: b32 reads 2-way (free)
  __shared__ float qs[4][64];
  __shared__ float ps[4][256];
  const int bh = blockIdx.x;
  const int b = bh / NH, h = bh - b * NH;
  const float* Kp = Kg + (size_t)bh * SEQL * 64;
  const float* Vp = Vg + (size_t)bh * SEQL * 64;
  const int tid = threadIdx.x;
  for (int idx = tid; idx < SEQL * 64; idx += 256) {
    int s = idx >> 6, d = idx & 63;
    Ks[s][d] = f2bf(Kp[idx]);
    Vt[d][s] = f2bf(Vp[idx]);
  }
  __syncthreads();
  const int wv = tid >> 6, lane = tid & 63;
  for (int j = 0; j < 50; ++j) {
    int s = wv + 4 * j;
    bool valid = (s < SEQL);
    if (valid) qs[wv][lane] = Q[((size_t)bh * SEQL + s) * 64 + lane] * ATT_SCALE;
    __syncthreads();
    float sc0 = 0.f, sc1 = 0.f, sc2 = 0.f, sc3 = 0.f;
    int k3 = lane + 192;
    bool k3v = (k3 < SEQL);
    int k3c = k3v ? k3 : 0;
#pragma unroll 4
    for (int d4 = 0; d4 < 16; ++d4) {
      float4 qv = *(float4*)&qs[wv][d4 * 4];
      ushort4 a0 = *(ushort4*)&Ks[lane][d4 * 4];
      ushort4 a1 = *(ushort4*)&Ks[lane + 64][d4 * 4];
      ushort4 a2 = *(ushort4*)&Ks[lane + 128][d4 * 4];
      ushort4 a3 = *(ushort4*)&Ks[k3c][d4 * 4];
      sc0 += qv.x * bf2f(a0.x) + qv.y * bf2f(a0.y) + qv.z * bf2f(a0.z) + qv.w * bf2f(a0.w);
      sc1 += qv.x * bf2f(a1.x) + qv.y * bf2f(a1.y) + qv.z * bf2f(a1.z) + qv.w * bf2f(a1.w);
      sc2 += qv.x * bf2f(a2.x) + qv.y * bf2f(a2.y) + qv.z * bf2f(a2.z) + qv.w * bf2f(a2.w);
      sc3 += qv.x * bf2f(a3.x) + qv.y * bf2f(a3.y) + qv.z * bf2f(a3.z) + qv.w * bf2f(a3.w);
    }
    if (!k3v) sc3 = -1e30f;
    float mx = fmaxf(fmaxf(sc0, sc1), fmaxf(sc2, sc3));
#pragma unroll
    for (int o = 32; o > 0; o >>= 1) mx = fmaxf(mx, __shfl_xor(mx, o));
    float p0 = expf(sc0 - mx);
    float p1 = expf(sc1 - mx);
    float p2 = expf(sc2 - mx);
    float p3 = k3v ? expf(sc3 - mx) : 0.f;
    float l = p0 + p1 + p2 + p3;
#pragma unroll
    for (int o = 32; o > 0; o >>= 1) l += __shfl_xor(l, o);
    ps[wv][lane] = p0;
    ps[wv][lane + 64] = p1;
    ps[wv][lane + 128] = p2;
    if (k3v) ps[wv][lane + 192] = p3;
    __syncthreads();
    float o = 0.f;
#pragma unroll 7
    for (int k4 = 0; k4 < 49; ++k4) {
      float4 pv = *(float4*)&ps[wv][k4 * 4];
      ushort2 v01 = *(ushort2*)&Vt[lane][k4 * 4];
      ushort2 v23 = *(ushort2*)&Vt[lane][k4 * 4 + 2];
      o += pv.x * bf2f(v01.x) + pv.y * bf2f(v01.y) + pv.z * bf2f(v23.x) + pv.w * bf2f(v23.y);
    }
    o += ps[wv][196] * bf2f(Vt[lane][196]);
    float oo = o / l;
    if (valid) X[((size_t)b * SEQL + s) * 768 + h * 64 + lane] += oo;
    __syncthreads();
  }
}

// ---------------- head: cls @ Whead + bhead -> softmax ----------------
__global__ __launch_bounds__(64) void head_kernel(const float* __restrict__ X,
                                                  const float* __restrict__ Wh,
                                                  const float* __restrict__ bh,
                                                  float* __restrict__ out) {
  __shared__ float lg[10];
  int b = blockIdx.x, t = threadIdx.x;
  if (t < 10) {
    float acc = bh[t];
    const float* x = X + (size_t)b * SEQL * 768;
    for (int d = 0; d < 768; ++d) acc += x[d] * Wh[d * 10 + t];
    lg[t] = acc;
  }
  __syncthreads();
  if (t == 0) {
    float m = lg[0];
    for (int c = 1; c < 10; ++c) m = fmaxf(m, lg[c]);
    float ssum = 0.f;
    for (int c = 0; c < 10; ++c) ssum += expf(lg[c] - m);
    for (int c = 0; c < 10; ++c) out[b * 10 + c] = expf(lg[c] - m) / ssum;
  }
}

extern "C" void kernel_launch(void* const* d_in, const int* in_sizes, int n_in,
                              void* d_out, int out_size, void* d_ws, size_t ws_size,
                              hipStream_t stream) {
  const float* images = (const float*)d_in[0];
  const float* Wmap = (const float*)d_in[1];
  const float* bmap = (const float*)d_in[2];
  const float* cls  = (const float*)d_in[3];
  const float* pos  = (const float*)d_in[4];
  const float* ln1g = (const float*)d_in[5];
  const float* ln1b = (const float*)d_in[6];
  const float* Wq   = (const float*)d_in[7];
  const float* bq   = (const float*)d_in[8];
  const float* Wk   = (const float*)d_in[9];
  const float* bk   = (const float*)d_in[10];
  const float* Wv   = (const float*)d_in[11];
  const float* bv   = (const float*)d_in[12];
  const float* ln2g = (const float*)d_in[13];
  const float* ln2b = (const float*)d_in[14];
  const float* W1   = (const float*)d_in[15];
  const float* b1   = (const float*)d_in[16];
  const float* W2   = (const float*)d_in[17];
  const float* b2   = (const float*)d_in[18];
  const float* Wh   = (const float*)d_in[19];
  const float* bhd  = (const float*)d_in[20];
  float* out = (float*)d_out;

  const size_t ACT = (size_t)TOKS * 768;        // 9,682,944 floats
  if (ws_size < (3 * ACT + 2 * ACT) * sizeof(float)) return;  // need ~193.7 MB

  float* X   = (float*)d_ws;
  float* Hb  = X + ACT;
  float* R   = Hb + ACT;          // region: patches | Q,K,V | MLP mid (chunked)
  float* Qb  = R;
  float* Kb  = R + ACT;
  float* Vb  = R + 2 * ACT;
  float* mid = R;                 // reused after attention

  patchify_kernel<<<9408, 256, 0, stream>>>(images, R);
  clspos_kernel<<<192, 256, 0, stream>>>(cls, pos, X);
  gemm128<0><<<dim3(6, 98), 256, 0, stream>>>(R, Wmap, X, bmap, pos, PTOK, 768, 768);

  for (int i = 0; i < NBLK; ++i) {
    ln_kernel<<<3152, 256, 0, stream>>>(X, Hb, ln1g + i * 768, ln1b + i * 768);
    qkv_kernel<<<dim3(394, 12), 256, 0, stream>>>(Hb,
        Wq + (size_t)i * 49152, bq + i * 768,
        Wk + (size_t)i * 49152, bk + i * 768,
        Wv + (size_t)i * 49152, bv + i * 768, Qb, Kb, Vb);
    attn_kernel<<<768, 256, 0, stream>>>(Qb, Kb, Vb, X);
    ln_kernel<<<3152, 256, 0, stream>>>(X, Hb, ln2g + i * 768, ln2b + i * 768);
    for (int ch = 0; ch < 2; ++ch) {
      gemm128<1><<<dim3(24, 50), 256, 0, stream>>>(Hb + (size_t)ch * 6304 * 768,
          W1 + (size_t)i * 2359296, mid, b1 + i * 3072, nullptr, 6304, MLPD, 768);
      gemm128<2><<<dim3(6, 50), 256, 0, stream>>>(mid,
          W2 + (size_t)i * 2359296, X + (size_t)ch * 6304 * 768, b2 + i * 768, nullptr,
          6304, 768, MLPD);
    }
  }
  head_kernel<<<64, 64, 0, stream>>>(X, Wh, bhd, out);
}

// Round 2
// 4427.395 us; speedup vs baseline: 3.2797x; 3.2797x over previous
//
#include <hip/hip_runtime.h>
#include <cstddef>

#define BATCH 64
#define SEQL  197
#define EMB   768
#define NH    12
#define HDIM  64
#define NBLK  6
#define MLPD  3072
#define TOKS  12608   // BATCH*SEQL
#define PTOK  12544   // BATCH*196
#define ATT_SCALE 0.28867513459481287f  // 1/sqrt(H=12)

typedef short bf16x8 __attribute__((ext_vector_type(8)));
typedef float f32x4  __attribute__((ext_vector_type(4)));

__device__ inline float bf2f(unsigned short u) {
  union { unsigned int i; float f; } c; c.i = ((unsigned int)u) << 16; return c.f;
}
__device__ inline unsigned short f2bf(float f) {
  union { float f; unsigned int i; } c; c.f = f;
  unsigned int r = c.i + 0x7FFFu + ((c.i >> 16) & 1u);
  return (unsigned short)(r >> 16);
}

__device__ __forceinline__ void gload16(const unsigned short* g, void* l) {
  __builtin_amdgcn_global_load_lds(
      (const __attribute__((address_space(1))) unsigned int*)g,
      (__attribute__((address_space(3))) unsigned int*)l, 16, 0, 0);
}

// ---------------- patchify: images (B,3,224,224) -> patches (12544, 768) bf16 ----------------
__global__ __launch_bounds__(256) void patchify_kernel(const float* __restrict__ img,
                                                       unsigned short* __restrict__ out) {
  int i4 = blockIdx.x * 256 + threadIdx.x;    // < 12544*768/4
  int f4 = i4 % 192;
  int r  = i4 / 192;
  int b  = r / 196, t = r - b * 196;
  int f  = f4 * 4;
  int c  = f >> 8;
  int rem = f & 255;
  int iy = rem >> 4, ix = rem & 15;
  int py = t / 14, px = t - py * 14;
  const float* src = img + ((((size_t)b * 3 + c) * 224 + py * 16 + iy) * 224 + px * 16 + ix);
  float4 v = *(const float4*)src;
  ushort4 u;
  u.x = f2bf(v.x); u.y = f2bf(v.y); u.z = f2bf(v.z); u.w = f2bf(v.w);
  *(ushort4*)(out + (size_t)r * 768 + f) = u;
}

// ---------------- cls token + pos row 0 ----------------
__global__ __launch_bounds__(256) void clspos_kernel(const float* __restrict__ cls,
                                                     const float* __restrict__ pos,
                                                     float* __restrict__ X) {
  int idx = blockIdx.x * 256 + threadIdx.x;   // < 64*768
  int b = idx / 768, e = idx - b * 768;
  X[(size_t)b * SEQL * 768 + e] = cls[e] + pos[e];
}

// ---------------- weight transpose+convert: W (K,N) fp32 -> Wt (N,K) bf16 ----------------
__global__ __launch_bounds__(256) void wconv_kernel(const float* __restrict__ W,
                                                    unsigned short* __restrict__ Wt,
                                                    int K, int N) {
  __shared__ float t[32][33];
  int k0 = blockIdx.x * 32, n0 = blockIdx.y * 32;
  int kk = threadIdx.x >> 3, nn = (threadIdx.x & 7) * 4;
  float4 v = *(const float4*)&W[(size_t)(k0 + kk) * N + n0 + nn];
  t[nn + 0][kk] = v.x; t[nn + 1][kk] = v.y; t[nn + 2][kk] = v.z; t[nn + 3][kk] = v.w;
  __syncthreads();
  int nr = threadIdx.x >> 3, kc = (threadIdx.x & 7) * 4;
  ushort4 u;
  u.x = f2bf(t[nr][kc + 0]); u.y = f2bf(t[nr][kc + 1]);
  u.z = f2bf(t[nr][kc + 2]); u.w = f2bf(t[nr][kc + 3]);
  *(ushort4*)&Wt[(size_t)(n0 + nr) * K + k0 + kc] = u;
}

// ---------------- bf16 MFMA GEMM: C(M,N) = A(M,K) @ Bt(N,K)^T, 128x128 tile, BK=64 ----------
// MODE 0: X rows remapped b*197+1+t, C = acc + bias + pos[1+t]   (fp32 out)
// MODE 1: C = gelu(acc + bias)  -> bf16 out (mid, N=3072)
// MODE 2: C += acc + bias       -> fp32 residual (X, N=768)
template<int MODE>
__global__ __launch_bounds__(256) void gemm_mfma(const unsigned short* __restrict__ A, int lda,
                                                 const unsigned short* __restrict__ Bt, int ldb,
                                                 void* __restrict__ Cv,
                                                 const float* __restrict__ bias,
                                                 const float* __restrict__ pos,
                                                 int M, int N, int K) {
  __shared__ short As[8192];   // [128 rows][64 k] bf16, chunk-swizzled
  __shared__ short Bs[8192];   // [128 n-rows][64 k]
  const int tid  = threadIdx.x;
  const int wid  = tid >> 6, lane = tid & 63;
  const int wr   = wid >> 1, wc = wid & 1;     // wave -> 64x64 quadrant
  const int fr   = lane & 15;                  // fragment row (A) / col (B,D)
  const int fq   = lane >> 4;                  // k-quad
  const int m0   = blockIdx.y * 128;
  const int n0   = blockIdx.x * 128;
  const int srow = lane >> 3;                  // staging row within 8-row group
  const int schk = lane & 7;                   // staging 16B chunk
  const int Mc   = M - 1;

  f32x4 acc[4][4];
#pragma unroll
  for (int m = 0; m < 4; ++m)
#pragma unroll
    for (int n = 0; n < 4; ++n) acc[m][n] = (f32x4)0.f;

  for (int k0 = 0; k0 < K; k0 += 64) {
#pragma unroll
    for (int i = 0; i < 4; ++i) {
      int row = i * 32 + wid * 8 + srow;
      int gr = m0 + row; if (gr > Mc) gr = Mc;
      gload16(A + (size_t)gr * lda + k0 + ((schk ^ (row & 7)) << 3),
              (char*)As + i * 4096 + wid * 1024);
      gload16(Bt + (size_t)(n0 + row) * ldb + k0 + ((schk ^ (row & 7)) << 3),
              (char*)Bs + i * 4096 + wid * 1024);
    }
    __syncthreads();
#pragma unroll
    for (int ks = 0; ks < 2; ++ks) {
      bf16x8 af[4], bfr[4];
#pragma unroll
      for (int m = 0; m < 4; ++m) {
        int row = (wr << 6) + (m << 4) + fr;
        int ch = ((ks << 2) + fq) ^ (row & 7);
        af[m] = *(const bf16x8*)&As[(row << 6) + (ch << 3)];
      }
#pragma unroll
      for (int n = 0; n < 4; ++n) {
        int row = (wc << 6) + (n << 4) + fr;
        int ch = ((ks << 2) + fq) ^ (row & 7);
        bfr[n] = *(const bf16x8*)&Bs[(row << 6) + (ch << 3)];
      }
#pragma unroll
      for (int m = 0; m < 4; ++m)
#pragma unroll
        for (int n = 0; n < 4; ++n)
          acc[m][n] = __builtin_amdgcn_mfma_f32_16x16x32_bf16(af[m], bfr[n], acc[m][n], 0, 0, 0);
    }
    __syncthreads();
  }

  // epilogue: D row = (lane>>4)*4 + reg, col = lane&15  [m91-verified]
#pragma unroll
  for (int m = 0; m < 4; ++m) {
#pragma unroll
    for (int j = 0; j < 4; ++j) {
      int r = m0 + (wr << 6) + (m << 4) + (fq << 2) + j;
      if (r >= M) continue;
#pragma unroll
      for (int n = 0; n < 4; ++n) {
        int c = n0 + (wc << 6) + (n << 4) + fr;
        float v = acc[m][n][j] + bias[c];
        if (MODE == 0) {
          int b = r / 196, t = r - b * 196;
          ((float*)Cv)[((size_t)b * SEQL + 1 + t) * 768 + c] = v + pos[(size_t)(1 + t) * 768 + c];
        } else if (MODE == 1) {
          float g = 0.5f * v * (1.f + erff(v * 0.70710678118654752f));
          ((unsigned short*)Cv)[(size_t)r * MLPD + c] = f2bf(g);
        } else {
          ((float*)Cv)[(size_t)r * 768 + c] += v;
        }
      }
    }
  }
}

// ---------------- LayerNorm: one wave per token, fp32 in -> bf16 out ----------------
__global__ __launch_bounds__(256) void ln_kernel(const float* __restrict__ Xi,
                                                 unsigned short* __restrict__ Ho,
                                                 const float* __restrict__ g,
                                                 const float* __restrict__ bb) {
  int tok = blockIdx.x * 4 + (threadIdx.x >> 6);
  int lane = threadIdx.x & 63;
  const float* x = Xi + (size_t)tok * 768;
  float4 v0 = *(const float4*)(x + lane * 4);
  float4 v1 = *(const float4*)(x + 256 + lane * 4);
  float4 v2 = *(const float4*)(x + 512 + lane * 4);
  float s = v0.x + v0.y + v0.z + v0.w + v1.x + v1.y + v1.z + v1.w + v2.x + v2.y + v2.z + v2.w;
  float q = v0.x*v0.x + v0.y*v0.y + v0.z*v0.z + v0.w*v0.w
          + v1.x*v1.x + v1.y*v1.y + v1.z*v1.z + v1.w*v1.w
          + v2.x*v2.x + v2.y*v2.y + v2.z*v2.z + v2.w*v2.w;
#pragma unroll
  for (int o = 32; o > 0; o >>= 1) { s += __shfl_xor(s, o); q += __shfl_xor(q, o); }
  float mean = s * (1.f / 768.f);
  float var  = q * (1.f / 768.f) - mean * mean;
  float rs = rsqrtf(var + 1e-5f);
  unsigned short* outp = Ho + (size_t)tok * 768;
  float4 g0 = *(const float4*)(g + lane * 4);
  float4 g1 = *(const float4*)(g + 256 + lane * 4);
  float4 g2 = *(const float4*)(g + 512 + lane * 4);
  float4 b0 = *(const float4*)(bb + lane * 4);
  float4 b1 = *(const float4*)(bb + 256 + lane * 4);
  float4 b2 = *(const float4*)(bb + 512 + lane * 4);
  ushort4 s0, s1, s2;
  s0.x = f2bf((v0.x - mean) * rs * g0.x + b0.x); s0.y = f2bf((v0.y - mean) * rs * g0.y + b0.y);
  s0.z = f2bf((v0.z - mean) * rs * g0.z + b0.z); s0.w = f2bf((v0.w - mean) * rs * g0.w + b0.w);
  s1.x = f2bf((v1.x - mean) * rs * g1.x + b1.x); s1.y = f2bf((v1.y - mean) * rs * g1.y + b1.y);
  s1.z = f2bf((v1.z - mean) * rs * g1.z + b1.z); s1.w = f2bf((v1.w - mean) * rs * g1.w + b1.w);
  s2.x = f2bf((v2.x - mean) * rs * g2.x + b2.x); s2.y = f2bf((v2.y - mean) * rs * g2.y + b2.y);
  s2.z = f2bf((v2.z - mean) * rs * g2.z + b2.z); s2.w = f2bf((v2.w - mean) * rs * g2.w + b2.w);
  *(ushort4*)(outp + lane * 4) = s0;
  *(ushort4*)(outp + 256 + lane * 4) = s1;
  *(ushort4*)(outp + 512 + lane * 4) = s2;
}

// ---------------- per-head QKV: block = (32 tokens, head h), bf16 input ----------------
__global__ __launch_bounds__(256) void qkv_kernel(const unsigned short* __restrict__ Hb,
    const float* __restrict__ Wq, const float* __restrict__ bq,
    const float* __restrict__ Wk, const float* __restrict__ bk,
    const float* __restrict__ Wv, const float* __restrict__ bv,
    float* __restrict__ Qo, float* __restrict__ Ko, float* __restrict__ Vo) {
  __shared__ float xs[32][68];
  __shared__ float ws[3][64][64];
  const int h = blockIdx.y;
  const int tk0 = blockIdx.x * 32;
  const int tid = threadIdx.x;
  {
    int tok = tid >> 3;
    int p = (tid & 7) * 8;
    const unsigned short* src = Hb + (size_t)(tk0 + tok) * 768 + h * 64 + p;
    ushort4 u0 = *(const ushort4*)src;
    ushort4 u1 = *(const ushort4*)(src + 4);
    xs[tok][p + 0] = bf2f(u0.x); xs[tok][p + 1] = bf2f(u0.y);
    xs[tok][p + 2] = bf2f(u0.z); xs[tok][p + 3] = bf2f(u0.w);
    xs[tok][p + 4] = bf2f(u1.x); xs[tok][p + 5] = bf2f(u1.y);
    xs[tok][p + 6] = bf2f(u1.z); xs[tok][p + 7] = bf2f(u1.w);
  }
  {
    const float* w0 = Wq + (size_t)h * 4096;
    const float* w1 = Wk + (size_t)h * 4096;
    const float* w2 = Wv + (size_t)h * 4096;
    int base = tid * 16;
    float* wf = &ws[0][0][0];
#pragma unroll
    for (int j = 0; j < 16; j += 4) {
      *(float4*)(wf + base + j)        = *(const float4*)(w0 + base + j);
      *(float4*)(wf + 4096 + base + j) = *(const float4*)(w1 + base + j);
      *(float4*)(wf + 8192 + base + j) = *(const float4*)(w2 + base + j);
    }
  }
  __syncthreads();
  const int e4 = (tid & 15) * 4;
  const int t2 = (tid >> 4) * 2;
  float acc[3][2][4];
#pragma unroll
  for (int m = 0; m < 3; ++m)
#pragma unroll
    for (int ti = 0; ti < 2; ++ti)
#pragma unroll
      for (int j = 0; j < 4; ++j) acc[m][ti][j] = 0.f;

#pragma unroll 4
  for (int d4 = 0; d4 < 16; ++d4) {
    float x0[4], x1[4];
    *(float4*)x0 = *(float4*)&xs[t2][d4 * 4];
    *(float4*)x1 = *(float4*)&xs[t2 + 1][d4 * 4];
#pragma unroll
    for (int m = 0; m < 3; ++m)
#pragma unroll
      for (int dj = 0; dj < 4; ++dj) {
        float4 w = *(float4*)&ws[m][d4 * 4 + dj][e4];
        acc[m][0][0] += x0[dj] * w.x; acc[m][0][1] += x0[dj] * w.y;
        acc[m][0][2] += x0[dj] * w.z; acc[m][0][3] += x0[dj] * w.w;
        acc[m][1][0] += x1[dj] * w.x; acc[m][1][1] += x1[dj] * w.y;
        acc[m][1][2] += x1[dj] * w.z; acc[m][1][3] += x1[dj] * w.w;
      }
  }
#pragma unroll
  for (int m = 0; m < 3; ++m) {
    const float* bptr = (m == 0 ? bq : (m == 1 ? bk : bv)) + h * 64 + e4;
    float* optr = (m == 0 ? Qo : (m == 1 ? Ko : Vo));
#pragma unroll
    for (int ti = 0; ti < 2; ++ti) {
      int tk = tk0 + t2 + ti;
      int b = tk / 197, s = tk - b * 197;
      size_t base_o = (((size_t)b * NH + h) * SEQL + s) * 64 + e4;
      float4 o;
      o.x = acc[m][ti][0] + bptr[0];
      o.y = acc[m][ti][1] + bptr[1];
      o.z = acc[m][ti][2] + bptr[2];
      o.w = acc[m][ti][3] + bptr[3];
      *(float4*)&optr[base_o] = o;
    }
  }
}

// ---------------- attention: one WG per (b,h); K/V staged bf16 in LDS ----------------
__global__ __launch_bounds__(256) void attn_kernel(const float* __restrict__ Q,
                                                   const float* __restrict__ Kg,
                                                   const float* __restrict__ Vg,
                                                   float* __restrict__ X) {
  __shared__ unsigned short Ks[197][68];
  __shared__ unsigned short Vt[64][198];
  __shared__ float qs[4][64];
  __shared__ float ps[4][256];
  const int bh = blockIdx.x;
  const int b = bh / NH, h = bh - b * NH;
  const float* Kp = Kg + (size_t)bh * SEQL * 64;
  const float* Vp = Vg + (size_t)bh * SEQL * 64;
  const int tid = threadIdx.x;
  for (int idx = tid; idx < SEQL * 64; idx += 256) {
    int s = idx >> 6, d = idx & 63;
    Ks[s][d] = f2bf(Kp[idx]);
    Vt[d][s] = f2bf(Vp[idx]);
  }
  __syncthreads();
  const int wv = tid >> 6, lane = tid & 63;
  for (int j = 0; j < 50; ++j) {
    int s = wv + 4 * j;
    bool valid = (s < SEQL);
    if (valid) qs[wv][lane] = Q[((size_t)bh * SEQL + s) * 64 + lane] * ATT_SCALE;
    __syncthreads();
    float sc0 = 0.f, sc1 = 0.f, sc2 = 0.f, sc3 = 0.f;
    int k3 = lane + 192;
    bool k3v = (k3 < SEQL);
    int k3c = k3v ? k3 : 0;
#pragma unroll 4
    for (int d4 = 0; d4 < 16; ++d4) {
      float4 qv = *(float4*)&qs[wv][d4 * 4];
      ushort4 a0 = *(ushort4*)&Ks[lane][d4 * 4];
      ushort4 a1 = *(ushort4*)&Ks[lane + 64][d4 * 4];
      ushort4 a2 = *(ushort4*)&Ks[lane + 128][d4 * 4];
      ushort4 a3 = *(ushort4*)&Ks[k3c][d4 * 4];
      sc0 += qv.x * bf2f(a0.x) + qv.y * bf2f(a0.y) + qv.z * bf2f(a0.z) + qv.w * bf2f(a0.w);
      sc1 += qv.x * bf2f(a1.x) + qv.y * bf2f(a1.y) + qv.z * bf2f(a1.z) + qv.w * bf2f(a1.w);
      sc2 += qv.x * bf2f(a2.x) + qv.y * bf2f(a2.y) + qv.z * bf2f(a2.z) + qv.w * bf2f(a2.w);
      sc3 += qv.x * bf2f(a3.x) + qv.y * bf2f(a3.y) + qv.z * bf2f(a3.z) + qv.w * bf2f(a3.w);
    }
    if (!k3v) sc3 = -1e30f;
    float mx = fmaxf(fmaxf(sc0, sc1), fmaxf(sc2, sc3));
#pragma unroll
    for (int o = 32; o > 0; o >>= 1) mx = fmaxf(mx, __shfl_xor(mx, o));
    float p0 = expf(sc0 - mx);
    float p1 = expf(sc1 - mx);
    float p2 = expf(sc2 - mx);
    float p3 = k3v ? expf(sc3 - mx) : 0.f;
    float l = p0 + p1 + p2 + p3;
#pragma unroll
    for (int o = 32; o > 0; o >>= 1) l += __shfl_xor(l, o);
    ps[wv][lane] = p0;
    ps[wv][lane + 64] = p1;
    ps[wv][lane + 128] = p2;
    if (k3v) ps[wv][lane + 192] = p3;
    __syncthreads();
    float o = 0.f;
#pragma unroll 7
    for (int k4 = 0; k4 < 49; ++k4) {
      float4 pv = *(float4*)&ps[wv][k4 * 4];
      ushort2 v01 = *(ushort2*)&Vt[lane][k4 * 4];
      ushort2 v23 = *(ushort2*)&Vt[lane][k4 * 4 + 2];
      o += pv.x * bf2f(v01.x) + pv.y * bf2f(v01.y) + pv.z * bf2f(v23.x) + pv.w * bf2f(v23.y);
    }
    o += ps[wv][196] * bf2f(Vt[lane][196]);
    float oo = o / l;
    if (valid) X[((size_t)b * SEQL + s) * 768 + h * 64 + lane] += oo;
    __syncthreads();
  }
}

// ---------------- head: cls @ Whead + bhead -> softmax ----------------
__global__ __launch_bounds__(64) void head_kernel(const float* __restrict__ X,
                                                  const float* __restrict__ Wh,
                                                  const float* __restrict__ bh,
                                                  float* __restrict__ out) {
  __shared__ float lg[10];
  int b = blockIdx.x, t = threadIdx.x;
  if (t < 10) {
    float acc = bh[t];
    const float* x = X + (size_t)b * SEQL * 768;
    for (int d = 0; d < 768; ++d) acc += x[d] * Wh[d * 10 + t];
    lg[t] = acc;
  }
  __syncthreads();
  if (t == 0) {
    float m = lg[0];
    for (int c = 1; c < 10; ++c) m = fmaxf(m, lg[c]);
    float ssum = 0.f;
    for (int c = 0; c < 10; ++c) ssum += expf(lg[c] - m);
    for (int c = 0; c < 10; ++c) out[b * 10 + c] = expf(lg[c] - m) / ssum;
  }
}

extern "C" void kernel_launch(void* const* d_in, const int* in_sizes, int n_in,
                              void* d_out, int out_size, void* d_ws, size_t ws_size,
                              hipStream_t stream) {
  const float* images = (const float*)d_in[0];
  const float* Wmap = (const float*)d_in[1];
  const float* bmap = (const float*)d_in[2];
  const float* cls  = (const float*)d_in[3];
  const float* pos  = (const float*)d_in[4];
  const float* ln1g = (const float*)d_in[5];
  const float* ln1b = (const float*)d_in[6];
  const float* Wq   = (const float*)d_in[7];
  const float* bq   = (const float*)d_in[8];
  const float* Wk   = (const float*)d_in[9];
  const float* bk   = (const float*)d_in[10];
  const float* Wv   = (const float*)d_in[11];
  const float* bv   = (const float*)d_in[12];
  const float* ln2g = (const float*)d_in[13];
  const float* ln2b = (const float*)d_in[14];
  const float* W1   = (const float*)d_in[15];
  const float* b1   = (const float*)d_in[16];
  const float* W2   = (const float*)d_in[17];
  const float* b2   = (const float*)d_in[18];
  const float* Wh   = (const float*)d_in[19];
  const float* bhd  = (const float*)d_in[20];
  float* out = (float*)d_out;

  const size_t ACT = (size_t)TOKS * 768;
  // layout (bytes): X fp32 | Hb bf16 | R (QKV fp32 / mid bf16 / patches bf16) | W1t | W2t | Wmapt
  const size_t oX = 0;
  const size_t oHb = oX + ACT * 4;                 // 38,731,776
  const size_t oR  = oHb + ACT * 2;                // 58,097,664
  const size_t oW1 = oR + 3 * ACT * 4;             // 174,292,992
  const size_t oW2 = oW1 + (size_t)768 * 3072 * 2; // 179,011,584
  const size_t oWm = oW2 + (size_t)768 * 3072 * 2; // 183,730,176
  const size_t need = oWm + (size_t)768 * 768 * 2; // 184,909,824
  if (ws_size < need) return;

  char* ws = (char*)d_ws;
  float* X = (float*)(ws + oX);
  unsigned short* Hb = (unsigned short*)(ws + oHb);
  float* Qb = (float*)(ws + oR);
  float* Kb = Qb + ACT;
  float* Vb = Kb + ACT;
  unsigned short* mid = (unsigned short*)(ws + oR);      // reused after QKV consumed
  unsigned short* patches = (unsigned short*)(ws + oR);  // dead before QKV written
  unsigned short* W1t = (unsigned short*)(ws + oW1);
  unsigned short* W2t = (unsigned short*)(ws + oW2);
  unsigned short* Wmapt = (unsigned short*)(ws + oWm);

  wconv_kernel<<<dim3(24, 24), 256, 0, stream>>>(Wmap, Wmapt, 768, 768);
  patchify_kernel<<<9408, 256, 0, stream>>>(images, patches);
  clspos_kernel<<<192, 256, 0, stream>>>(cls, pos, X);
  gemm_mfma<0><<<dim3(6, 98), 256, 0, stream>>>(patches, 768, Wmapt, 768, X, bmap, pos,
                                                PTOK, 768, 768);

  for (int i = 0; i < NBLK; ++i) {
    ln_kernel<<<3152, 256, 0, stream>>>(X, Hb, ln1g + i * 768, ln1b + i * 768);
    qkv_kernel<<<dim3(394, 12), 256, 0, stream>>>(Hb,
        Wq + (size_t)i * 49152, bq + i * 768,
        Wk + (size_t)i * 49152, bk + i * 768,
        Wv + (size_t)i * 49152, bv + i * 768, Qb, Kb, Vb);
    attn_kernel<<<768, 256, 0, stream>>>(Qb, Kb, Vb, X);
    ln_kernel<<<3152, 256, 0, stream>>>(X, Hb, ln2g + i * 768, ln2b + i * 768);
    wconv_kernel<<<dim3(24, 96), 256, 0, stream>>>(W1 + (size_t)i * 2359296, W1t, 768, MLPD);
    wconv_kernel<<<dim3(96, 24), 256, 0, stream>>>(W2 + (size_t)i * 2359296, W2t, MLPD, 768);
    gemm_mfma<1><<<dim3(24, 99), 256, 0, stream>>>(Hb, 768, W1t, 768, mid, b1 + i * MLPD,
                                                   nullptr, TOKS, MLPD, 768);
    gemm_mfma<2><<<dim3(6, 99), 256, 0, stream>>>(mid, MLPD, W2t, MLPD, X, b2 + i * 768,
                                                  nullptr, TOKS, 768, MLPD);
  }
  head_kernel<<<64, 64, 0, stream>>>(X, Wh, bhd, out);
}

// Round 3
// 2149.825 us; speedup vs baseline: 6.7543x; 2.0594x over previous
//
#include <hip/hip_runtime.h>
#include <cstddef>

#define BATCH 64
#define SEQL  197
#define EMB   768
#define NH    12
#define HDIM  64
#define NBLK  6
#define MLPD  3072
#define TOKS  12608   // BATCH*SEQL
#define PTOK  12544   // BATCH*196
#define ATT_SCALE 0.28867513459481287f  // 1/sqrt(H=12)
#define LOG2E 1.4426950408889634f

typedef short bf16x8 __attribute__((ext_vector_type(8)));
typedef float f32x4  __attribute__((ext_vector_type(4)));

__device__ inline float bf2f(unsigned short u) {
  union { unsigned int i; float f; } c; c.i = ((unsigned int)u) << 16; return c.f;
}
__device__ inline unsigned short f2bf(float f) {
  union { float f; unsigned int i; } c; c.f = f;
  unsigned int r = c.i + 0x7FFFu + ((c.i >> 16) & 1u);
  return (unsigned short)(r >> 16);
}

__device__ __forceinline__ void gload16(const unsigned short* g, void* l) {
  __builtin_amdgcn_global_load_lds(
      (const __attribute__((address_space(1))) unsigned int*)g,
      (__attribute__((address_space(3))) unsigned int*)l, 16, 0, 0);
}

// ---------------- patchify: images (B,3,224,224) -> patches (12544, 768) bf16 ----------------
__global__ __launch_bounds__(256) void patchify_kernel(const float* __restrict__ img,
                                                       unsigned short* __restrict__ out) {
  int i4 = blockIdx.x * 256 + threadIdx.x;    // < 12544*768/4
  int f4 = i4 % 192;
  int r  = i4 / 192;
  int b  = r / 196, t = r - b * 196;
  int f  = f4 * 4;
  int c  = f >> 8;
  int rem = f & 255;
  int iy = rem >> 4, ix = rem & 15;
  int py = t / 14, px = t - py * 14;
  const float* src = img + ((((size_t)b * 3 + c) * 224 + py * 16 + iy) * 224 + px * 16 + ix);
  float4 v = *(const float4*)src;
  ushort4 u;
  u.x = f2bf(v.x); u.y = f2bf(v.y); u.z = f2bf(v.z); u.w = f2bf(v.w);
  *(ushort4*)(out + (size_t)r * 768 + f) = u;
}

// ---------------- cls token + pos row 0 ----------------
__global__ __launch_bounds__(256) void clspos_kernel(const float* __restrict__ cls,
                                                     const float* __restrict__ pos,
                                                     float* __restrict__ X) {
  int idx = blockIdx.x * 256 + threadIdx.x;   // < 64*768
  int b = idx / 768, e = idx - b * 768;
  X[(size_t)b * SEQL * 768 + e] = cls[e] + pos[e];
}

// ---------------- weight transpose+convert: W (K,N) fp32 -> Wt (N,K) bf16 ----------------
__global__ __launch_bounds__(256) void wconv_kernel(const float* __restrict__ W,
                                                    unsigned short* __restrict__ Wt,
                                                    int K, int N) {
  __shared__ float t[32][33];
  int k0 = blockIdx.x * 32, n0 = blockIdx.y * 32;
  int kk = threadIdx.x >> 3, nn = (threadIdx.x & 7) * 4;
  float4 v = *(const float4*)&W[(size_t)(k0 + kk) * N + n0 + nn];
  t[nn + 0][kk] = v.x; t[nn + 1][kk] = v.y; t[nn + 2][kk] = v.z; t[nn + 3][kk] = v.w;
  __syncthreads();
  int nr = threadIdx.x >> 3, kc = (threadIdx.x & 7) * 4;
  ushort4 u;
  u.x = f2bf(t[nr][kc + 0]); u.y = f2bf(t[nr][kc + 1]);
  u.z = f2bf(t[nr][kc + 2]); u.w = f2bf(t[nr][kc + 3]);
  *(ushort4*)&Wt[(size_t)(n0 + nr) * K + k0 + kc] = u;
}

// ---------------- bf16 MFMA GEMM: C(M,N) = A(M,K) @ Bt(N,K)^T, 128x128 tile, BK=64 ----------
template<int MODE>
__global__ __launch_bounds__(256) void gemm_mfma(const unsigned short* __restrict__ A, int lda,
                                                 const unsigned short* __restrict__ Bt, int ldb,
                                                 void* __restrict__ Cv,
                                                 const float* __restrict__ bias,
                                                 const float* __restrict__ pos,
                                                 int M, int N, int K) {
  __shared__ short As[8192];   // [128 rows][64 k] bf16, chunk-swizzled
  __shared__ short Bs[8192];
  const int tid  = threadIdx.x;
  const int wid  = tid >> 6, lane = tid & 63;
  const int wr   = wid >> 1, wc = wid & 1;
  const int fr   = lane & 15;
  const int fq   = lane >> 4;
  const int m0   = blockIdx.y * 128;
  const int n0   = blockIdx.x * 128;
  const int srow = lane >> 3;
  const int schk = lane & 7;
  const int Mc   = M - 1;

  f32x4 acc[4][4];
#pragma unroll
  for (int m = 0; m < 4; ++m)
#pragma unroll
    for (int n = 0; n < 4; ++n) acc[m][n] = (f32x4)0.f;

  for (int k0 = 0; k0 < K; k0 += 64) {
#pragma unroll
    for (int i = 0; i < 4; ++i) {
      int row = i * 32 + wid * 8 + srow;
      int gr = m0 + row; if (gr > Mc) gr = Mc;
      gload16(A + (size_t)gr * lda + k0 + ((schk ^ (row & 7)) << 3),
              (char*)As + i * 4096 + wid * 1024);
      gload16(Bt + (size_t)(n0 + row) * ldb + k0 + ((schk ^ (row & 7)) << 3),
              (char*)Bs + i * 4096 + wid * 1024);
    }
    __syncthreads();
#pragma unroll
    for (int ks = 0; ks < 2; ++ks) {
      bf16x8 af[4], bfr[4];
#pragma unroll
      for (int m = 0; m < 4; ++m) {
        int row = (wr << 6) + (m << 4) + fr;
        int ch = ((ks << 2) + fq) ^ (row & 7);
        af[m] = *(const bf16x8*)&As[(row << 6) + (ch << 3)];
      }
#pragma unroll
      for (int n = 0; n < 4; ++n) {
        int row = (wc << 6) + (n << 4) + fr;
        int ch = ((ks << 2) + fq) ^ (row & 7);
        bfr[n] = *(const bf16x8*)&Bs[(row << 6) + (ch << 3)];
      }
#pragma unroll
      for (int m = 0; m < 4; ++m)
#pragma unroll
        for (int n = 0; n < 4; ++n)
          acc[m][n] = __builtin_amdgcn_mfma_f32_16x16x32_bf16(af[m], bfr[n], acc[m][n], 0, 0, 0);
    }
    __syncthreads();
  }

#pragma unroll
  for (int m = 0; m < 4; ++m) {
#pragma unroll
    for (int j = 0; j < 4; ++j) {
      int r = m0 + (wr << 6) + (m << 4) + (fq << 2) + j;
      if (r >= M) continue;
#pragma unroll
      for (int n = 0; n < 4; ++n) {
        int c = n0 + (wc << 6) + (n << 4) + fr;
        float v = acc[m][n][j] + bias[c];
        if (MODE == 0) {
          int b = r / 196, t = r - b * 196;
          ((float*)Cv)[((size_t)b * SEQL + 1 + t) * 768 + c] = v + pos[(size_t)(1 + t) * 768 + c];
        } else if (MODE == 1) {
          float g = 0.5f * v * (1.f + erff(v * 0.70710678118654752f));
          ((unsigned short*)Cv)[(size_t)r * MLPD + c] = f2bf(g);
        } else {
          ((float*)Cv)[(size_t)r * 768 + c] += v;
        }
      }
    }
  }
}

// ---------------- LayerNorm: one wave per token, fp32 in -> bf16 out ----------------
__global__ __launch_bounds__(256) void ln_kernel(const float* __restrict__ Xi,
                                                 unsigned short* __restrict__ Ho,
                                                 const float* __restrict__ g,
                                                 const float* __restrict__ bb) {
  int tok = blockIdx.x * 4 + (threadIdx.x >> 6);
  int lane = threadIdx.x & 63;
  const float* x = Xi + (size_t)tok * 768;
  float4 v0 = *(const float4*)(x + lane * 4);
  float4 v1 = *(const float4*)(x + 256 + lane * 4);
  float4 v2 = *(const float4*)(x + 512 + lane * 4);
  float s = v0.x + v0.y + v0.z + v0.w + v1.x + v1.y + v1.z + v1.w + v2.x + v2.y + v2.z + v2.w;
  float q = v0.x*v0.x + v0.y*v0.y + v0.z*v0.z + v0.w*v0.w
          + v1.x*v1.x + v1.y*v1.y + v1.z*v1.z + v1.w*v1.w
          + v2.x*v2.x + v2.y*v2.y + v2.z*v2.z + v2.w*v2.w;
#pragma unroll
  for (int o = 32; o > 0; o >>= 1) { s += __shfl_xor(s, o); q += __shfl_xor(q, o); }
  float mean = s * (1.f / 768.f);
  float var  = q * (1.f / 768.f) - mean * mean;
  float rs = rsqrtf(var + 1e-5f);
  unsigned short* outp = Ho + (size_t)tok * 768;
  float4 g0 = *(const float4*)(g + lane * 4);
  float4 g1 = *(const float4*)(g + 256 + lane * 4);
  float4 g2 = *(const float4*)(g + 512 + lane * 4);
  float4 b0 = *(const float4*)(bb + lane * 4);
  float4 b1 = *(const float4*)(bb + 256 + lane * 4);
  float4 b2 = *(const float4*)(bb + 512 + lane * 4);
  ushort4 s0, s1, s2;
  s0.x = f2bf((v0.x - mean) * rs * g0.x + b0.x); s0.y = f2bf((v0.y - mean) * rs * g0.y + b0.y);
  s0.z = f2bf((v0.z - mean) * rs * g0.z + b0.z); s0.w = f2bf((v0.w - mean) * rs * g0.w + b0.w);
  s1.x = f2bf((v1.x - mean) * rs * g1.x + b1.x); s1.y = f2bf((v1.y - mean) * rs * g1.y + b1.y);
  s1.z = f2bf((v1.z - mean) * rs * g1.z + b1.z); s1.w = f2bf((v1.w - mean) * rs * g1.w + b1.w);
  s2.x = f2bf((v2.x - mean) * rs * g2.x + b2.x); s2.y = f2bf((v2.y - mean) * rs * g2.y + b2.y);
  s2.z = f2bf((v2.z - mean) * rs * g2.z + b2.z); s2.w = f2bf((v2.w - mean) * rs * g2.w + b2.w);
  *(ushort4*)(outp + lane * 4) = s0;
  *(ushort4*)(outp + 256 + lane * 4) = s1;
  *(ushort4*)(outp + 512 + lane * 4) = s2;
}

// ---------------- per-head QKV: block = (32 tokens, head h); bf16 out, Q pre-scaled ------
__global__ __launch_bounds__(256) void qkv_kernel(const unsigned short* __restrict__ Hb,
    const float* __restrict__ Wq, const float* __restrict__ bq,
    const float* __restrict__ Wk, const float* __restrict__ bk,
    const float* __restrict__ Wv, const float* __restrict__ bv,
    unsigned short* __restrict__ Qo, unsigned short* __restrict__ Ko,
    unsigned short* __restrict__ Vo) {
  __shared__ float xs[32][68];
  __shared__ float ws[3][64][64];
  const int h = blockIdx.y;
  const int tk0 = blockIdx.x * 32;
  const int tid = threadIdx.x;
  {
    int tok = tid >> 3;
    int p = (tid & 7) * 8;
    const unsigned short* src = Hb + (size_t)(tk0 + tok) * 768 + h * 64 + p;
    ushort4 u0 = *(const ushort4*)src;
    ushort4 u1 = *(const ushort4*)(src + 4);
    xs[tok][p + 0] = bf2f(u0.x); xs[tok][p + 1] = bf2f(u0.y);
    xs[tok][p + 2] = bf2f(u0.z); xs[tok][p + 3] = bf2f(u0.w);
    xs[tok][p + 4] = bf2f(u1.x); xs[tok][p + 5] = bf2f(u1.y);
    xs[tok][p + 6] = bf2f(u1.z); xs[tok][p + 7] = bf2f(u1.w);
  }
  {
    const float* w0 = Wq + (size_t)h * 4096;
    const float* w1 = Wk + (size_t)h * 4096;
    const float* w2 = Wv + (size_t)h * 4096;
    int base = tid * 16;
    float* wf = &ws[0][0][0];
#pragma unroll
    for (int j = 0; j < 16; j += 4) {
      *(float4*)(wf + base + j)        = *(const float4*)(w0 + base + j);
      *(float4*)(wf + 4096 + base + j) = *(const float4*)(w1 + base + j);
      *(float4*)(wf + 8192 + base + j) = *(const float4*)(w2 + base + j);
    }
  }
  __syncthreads();
  const int e4 = (tid & 15) * 4;
  const int t2 = (tid >> 4) * 2;
  float acc[3][2][4];
#pragma unroll
  for (int m = 0; m < 3; ++m)
#pragma unroll
    for (int ti = 0; ti < 2; ++ti)
#pragma unroll
      for (int j = 0; j < 4; ++j) acc[m][ti][j] = 0.f;

#pragma unroll 4
  for (int d4 = 0; d4 < 16; ++d4) {
    float x0[4], x1[4];
    *(float4*)x0 = *(float4*)&xs[t2][d4 * 4];
    *(float4*)x1 = *(float4*)&xs[t2 + 1][d4 * 4];
#pragma unroll
    for (int m = 0; m < 3; ++m)
#pragma unroll
      for (int dj = 0; dj < 4; ++dj) {
        float4 w = *(float4*)&ws[m][d4 * 4 + dj][e4];
        acc[m][0][0] += x0[dj] * w.x; acc[m][0][1] += x0[dj] * w.y;
        acc[m][0][2] += x0[dj] * w.z; acc[m][0][3] += x0[dj] * w.w;
        acc[m][1][0] += x1[dj] * w.x; acc[m][1][1] += x1[dj] * w.y;
        acc[m][1][2] += x1[dj] * w.z; acc[m][1][3] += x1[dj] * w.w;
      }
  }
#pragma unroll
  for (int m = 0; m < 3; ++m) {
    const float* bptr = (m == 0 ? bq : (m == 1 ? bk : bv)) + h * 64 + e4;
    unsigned short* optr = (m == 0 ? Qo : (m == 1 ? Ko : Vo));
    const float sc = (m == 0) ? ATT_SCALE : 1.f;
#pragma unroll
    for (int ti = 0; ti < 2; ++ti) {
      int tk = tk0 + t2 + ti;
      int b = tk / 197, s = tk - b * 197;
      size_t base_o = (((size_t)b * NH + h) * SEQL + s) * 64 + e4;
      ushort4 o;
      o.x = f2bf((acc[m][ti][0] + bptr[0]) * sc);
      o.y = f2bf((acc[m][ti][1] + bptr[1]) * sc);
      o.z = f2bf((acc[m][ti][2] + bptr[2]) * sc);
      o.w = f2bf((acc[m][ti][3] + bptr[3]) * sc);
      *(ushort4*)&optr[base_o] = o;
    }
  }
}

// ---------------- MFMA attention: one WG (4 waves) per (b,h) ----------------
// Q pre-scaled bf16 [bh][197][64]; K,V bf16 same layout.
__global__ __launch_bounds__(256) void attn_kernel(const unsigned short* __restrict__ Q,
                                                   const unsigned short* __restrict__ Kg,
                                                   const unsigned short* __restrict__ Vg,
                                                   float* __restrict__ X) {
  __shared__ unsigned short Vt[64][232];      // V^T; cols 197..232 zero
  __shared__ unsigned short Pl[4][16][232];   // per-wave P; cols >=208 zero
  const int bh = blockIdx.x;
  const int b = bh / NH, h = bh - b * NH;
  const int tid = threadIdx.x, wv = tid >> 6, lane = tid & 63;
  const int fr = lane & 15, hi = lane >> 4;   // hi in 0..3
  const unsigned short* Qp = Q  + (size_t)bh * SEQL * 64;
  const unsigned short* Kp = Kg + (size_t)bh * SEQL * 64;
  const unsigned short* Vp = Vg + (size_t)bh * SEQL * 64;

  // stage V transposed
  for (int idx = tid; idx < SEQL * 16; idx += 256) {
    int s = idx >> 4, d4 = (idx & 15) * 4;
    ushort4 v = *(const ushort4*)&Vp[s * 64 + d4];
    Vt[d4 + 0][s] = v.x; Vt[d4 + 1][s] = v.y; Vt[d4 + 2][s] = v.z; Vt[d4 + 3][s] = v.w;
  }
  for (int idx = tid; idx < 64 * 35; idx += 256) {       // zero Vt cols 197..231
    int d = idx / 35, c = 197 + idx % 35;
    Vt[d][c] = 0;
  }
  for (int idx = lane; idx < 16 * 24; idx += 64) {       // zero own P cols 208..231
    int r = idx / 24, c = 208 + idx % 24;
    Pl[wv][r][c] = 0;
  }
  __syncthreads();

  for (int qt = wv; qt < 13; qt += 4) {
    int qrow = qt * 16 + fr; if (qrow > 196) qrow = 196;
    bf16x8 qa0 = *(const bf16x8*)&Qp[qrow * 64 + hi * 8];
    bf16x8 qa1 = *(const bf16x8*)&Qp[qrow * 64 + 32 + hi * 8];
    f32x4 sc[13];
#pragma unroll
    for (int kt = 0; kt < 13; ++kt) {
      int krow = kt * 16 + fr; if (krow > 196) krow = 196;
      bf16x8 kb0 = *(const bf16x8*)&Kp[krow * 64 + hi * 8];
      bf16x8 kb1 = *(const bf16x8*)&Kp[krow * 64 + 32 + hi * 8];
      f32x4 a = (f32x4)0.f;
      a = __builtin_amdgcn_mfma_f32_16x16x32_bf16(qa0, kb0, a, 0, 0, 0);
      a = __builtin_amdgcn_mfma_f32_16x16x32_bf16(qa1, kb1, a, 0, 0, 0);
      sc[kt] = a;
    }
    // softmax over k; lane holds rows hi*4+j, col fr per tile
    float mx[4] = {-3e38f, -3e38f, -3e38f, -3e38f};
#pragma unroll
    for (int kt = 0; kt < 13; ++kt) {
      bool inval = (kt == 12) && (fr >= 5);
#pragma unroll
      for (int j = 0; j < 4; ++j) {
        float s = inval ? -3e38f : sc[kt][j];
        sc[kt][j] = s;
        mx[j] = fmaxf(mx[j], s);
      }
    }
#pragma unroll
    for (int o = 8; o > 0; o >>= 1)
#pragma unroll
      for (int j = 0; j < 4; ++j) mx[j] = fmaxf(mx[j], __shfl_xor(mx[j], o));
    float l[4] = {0.f, 0.f, 0.f, 0.f};
#pragma unroll
    for (int kt = 0; kt < 13; ++kt) {
#pragma unroll
      for (int j = 0; j < 4; ++j) {
        float p = exp2f((sc[kt][j] - mx[j]) * LOG2E);
        if ((kt == 12) && (fr >= 5)) p = 0.f;
        l[j] += p;
        Pl[wv][hi * 4 + j][kt * 16 + fr] = f2bf(p);
      }
    }
#pragma unroll
    for (int o = 8; o > 0; o >>= 1)
#pragma unroll
      for (int j = 0; j < 4; ++j) l[j] += __shfl_xor(l[j], o);
    // PV
    f32x4 ov[4];
#pragma unroll
    for (int n = 0; n < 4; ++n) ov[n] = (f32x4)0.f;
#pragma unroll
    for (int kc = 0; kc < 7; ++kc) {
      bf16x8 pa = *(const bf16x8*)&Pl[wv][fr][kc * 32 + hi * 8];
#pragma unroll
      for (int n = 0; n < 4; ++n) {
        bf16x8 vb = *(const bf16x8*)&Vt[n * 16 + fr][kc * 32 + hi * 8];
        ov[n] = __builtin_amdgcn_mfma_f32_16x16x32_bf16(pa, vb, ov[n], 0, 0, 0);
      }
    }
#pragma unroll
    for (int j = 0; j < 4; ++j) {
      int r = qt * 16 + hi * 4 + j;
      if (r >= SEQL) continue;
      float inv = 1.f / l[j];
      float* xp = X + ((size_t)b * SEQL + r) * 768 + h * 64 + fr;
#pragma unroll
      for (int n = 0; n < 4; ++n) xp[n * 16] += ov[n][j] * inv;
    }
  }
}

// ---------------- head: cls @ Whead + bhead -> softmax ----------------
__global__ __launch_bounds__(64) void head_kernel(const float* __restrict__ X,
                                                  const float* __restrict__ Wh,
                                                  const float* __restrict__ bh,
                                                  float* __restrict__ out) {
  __shared__ float lg[10];
  int b = blockIdx.x, t = threadIdx.x;
  if (t < 10) {
    float acc = bh[t];
    const float* x = X + (size_t)b * SEQL * 768;
    for (int d = 0; d < 768; ++d) acc += x[d] * Wh[d * 10 + t];
    lg[t] = acc;
  }
  __syncthreads();
  if (t == 0) {
    float m = lg[0];
    for (int c = 1; c < 10; ++c) m = fmaxf(m, lg[c]);
    float ssum = 0.f;
    for (int c = 0; c < 10; ++c) ssum += expf(lg[c] - m);
    for (int c = 0; c < 10; ++c) out[b * 10 + c] = expf(lg[c] - m) / ssum;
  }
}

extern "C" void kernel_launch(void* const* d_in, const int* in_sizes, int n_in,
                              void* d_out, int out_size, void* d_ws, size_t ws_size,
                              hipStream_t stream) {
  const float* images = (const float*)d_in[0];
  const float* Wmap = (const float*)d_in[1];
  const float* bmap = (const float*)d_in[2];
  const float* cls  = (const float*)d_in[3];
  const float* pos  = (const float*)d_in[4];
  const float* ln1g = (const float*)d_in[5];
  const float* ln1b = (const float*)d_in[6];
  const float* Wq   = (const float*)d_in[7];
  const float* bq   = (const float*)d_in[8];
  const float* Wk   = (const float*)d_in[9];
  const float* bk   = (const float*)d_in[10];
  const float* Wv   = (const float*)d_in[11];
  const float* bv   = (const float*)d_in[12];
  const float* ln2g = (const float*)d_in[13];
  const float* ln2b = (const float*)d_in[14];
  const float* W1   = (const float*)d_in[15];
  const float* b1   = (const float*)d_in[16];
  const float* W2   = (const float*)d_in[17];
  const float* b2   = (const float*)d_in[18];
  const float* Wh   = (const float*)d_in[19];
  const float* bhd  = (const float*)d_in[20];
  float* out = (float*)d_out;

  const size_t ACT = (size_t)TOKS * 768;
  const size_t oX = 0;
  const size_t oHb = oX + ACT * 4;
  const size_t oR  = oHb + ACT * 2;
  const size_t oW1 = oR + 3 * ACT * 4;
  const size_t oW2 = oW1 + (size_t)768 * 3072 * 2;
  const size_t oWm = oW2 + (size_t)768 * 3072 * 2;
  const size_t need = oWm + (size_t)768 * 768 * 2;
  if (ws_size < need) return;

  char* ws = (char*)d_ws;
  float* X = (float*)(ws + oX);
  unsigned short* Hb = (unsigned short*)(ws + oHb);
  unsigned short* Qb = (unsigned short*)(ws + oR);   // bf16 now
  unsigned short* Kb = Qb + ACT;
  unsigned short* Vb = Kb + ACT;
  unsigned short* mid = (unsigned short*)(ws + oR);
  unsigned short* patches = (unsigned short*)(ws + oR);
  unsigned short* W1t = (unsigned short*)(ws + oW1);
  unsigned short* W2t = (unsigned short*)(ws + oW2);
  unsigned short* Wmapt = (unsigned short*)(ws + oWm);

  wconv_kernel<<<dim3(24, 24), 256, 0, stream>>>(Wmap, Wmapt, 768, 768);
  patchify_kernel<<<9408, 256, 0, stream>>>(images, patches);
  clspos_kernel<<<192, 256, 0, stream>>>(cls, pos, X);
  gemm_mfma<0><<<dim3(6, 98), 256, 0, stream>>>(patches, 768, Wmapt, 768, X, bmap, pos,
                                                PTOK, 768, 768);

  for (int i = 0; i < NBLK; ++i) {
    ln_kernel<<<3152, 256, 0, stream>>>(X, Hb, ln1g + i * 768, ln1b + i * 768);
    qkv_kernel<<<dim3(394, 12), 256, 0, stream>>>(Hb,
        Wq + (size_t)i * 49152, bq + i * 768,
        Wk + (size_t)i * 49152, bk + i * 768,
        Wv + (size_t)i * 49152, bv + i * 768, Qb, Kb, Vb);
    attn_kernel<<<768, 256, 0, stream>>>(Qb, Kb, Vb, X);
    ln_kernel<<<3152, 256, 0, stream>>>(X, Hb, ln2g + i * 768, ln2b + i * 768);
    wconv_kernel<<<dim3(24, 96), 256, 0, stream>>>(W1 + (size_t)i * 2359296, W1t, 768, MLPD);
    wconv_kernel<<<dim3(96, 24), 256, 0, stream>>>(W2 + (size_t)i * 2359296, W2t, MLPD, 768);
    gemm_mfma<1><<<dim3(24, 99), 256, 0, stream>>>(Hb, 768, W1t, 768, mid, b1 + i * MLPD,
                                                   nullptr, TOKS, MLPD, 768);
    gemm_mfma<2><<<dim3(6, 99), 256, 0, stream>>>(mid, MLPD, W2t, MLPD, X, b2 + i * 768,
                                                  nullptr, TOKS, 768, MLPD);
  }
  head_kernel<<<64, 64, 0, stream>>>(X, Wh, bhd, out);
}